// Round 6
// baseline (203.081 us; speedup 1.0000x reference)
//
#include <hip/hip_runtime.h>
#include <hip/hip_bf16.h>
#include <math.h>

#define NBOX 19
#define NEDGE 171
#define TT 5
#define BATCH 2048
#define MP 32                 // padded rows per block (1 batch, 19 -> 32)

typedef __attribute__((ext_vector_type(8))) short short8v;
typedef __attribute__((ext_vector_type(4))) float f32x4;

static __device__ __forceinline__ ushort f2bf(float f) {
    __hip_bfloat16 h = __float2bfloat16(f);
    return *reinterpret_cast<ushort*>(&h);
}

static __device__ __forceinline__ float sigm(float x) {
    return __builtin_amdgcn_rcpf(1.0f + __expf(-x));
}

__device__ __forceinline__ int edge_index(int r, int c) {
    return r * (NBOX - 1) - (r * (r - 1)) / 2 + (c - r - 1);
}

// ---------------------------------------------------------------------------
// K1: per-batch normalized adjacency, bf16, padded to 32x32
// ---------------------------------------------------------------------------
__global__ __launch_bounds__(192) void adjbf_kernel(
    const float* __restrict__ loc,
    const int*   __restrict__ mask,
    const float* __restrict__ past,
    ushort* __restrict__ adjbf)
{
    int b = blockIdx.x;
    int tid = threadIdx.x;
    __shared__ float cx[NBOX], cy[NBOX], x0[NBOX], y0[NBOX], ndx[NBOX], ndy[NBOX];
    __shared__ int   mv[NBOX];
    __shared__ float w[NEDGE];
    __shared__ float dinv[NBOX];
    __shared__ float wmin_s, wmax_s;

    if (tid < NBOX) {
        const float* l = loc + ((size_t)b * NBOX + tid) * 5;
        cx[tid] = 0.5f * (l[1] + l[3]);
        cy[tid] = 0.5f * (l[2] + l[4]);
        const float* p0 = past + (((size_t)b * TT + 0) * NBOX + tid) * 6;
        const float* p4 = past + (((size_t)b * TT + (TT - 1)) * NBOX + tid) * 6;
        float cpx0 = (p0[3] - p0[1]) * 1280.0f, cpy0 = (p0[4] - p0[2]) * 720.0f;
        float cpx4 = (p4[3] - p4[1]) * 1280.0f, cpy4 = (p4[4] - p4[2]) * 720.0f;
        float dx = cpx4 - cpx0, dy = cpy4 - cpy0;
        float len = sqrtf(dx * dx + dy * dy);
        if (len == 0.0f) len = 1.0f;
        ndx[tid] = dx / len;
        ndy[tid] = dy / len;
        x0[tid] = cpx0;
        y0[tid] = cpy0;
        mv[tid] = mask[(size_t)b * NBOX + tid];
    }
    __syncthreads();

    float wv = 0.0f;
    if (tid < NEDGE) {
        int rem = tid, rr = 0;
        while (rem >= NBOX - 1 - rr) { rem -= NBOX - 1 - rr; rr++; }
        int r = rr, c = rr + 1 + rem;
        float ddx = cx[r] - cx[c], ddy = cy[r] - cy[c];
        float d = ddx * ddx + ddy * ddy;
        float ax = x0[r] + ndx[r] - x0[c] - ndx[c];
        float ay = y0[r] + ndy[r] - y0[c] - ndy[c];
        float d1 = sqrtf(ax * ax + ay * ay);
        float bx = x0[r] - x0[c], by = y0[r] - y0[c];
        float d2 = sqrtf(bx * bx + by * by);
        float md = d1 - d2;
        wv = expf(-(0.7f * d + 0.3f * md));
        if (!(mv[r] && mv[c])) wv = 0.0f;
        w[tid] = wv;
    }
    __syncthreads();

    if (tid == 0) {
        float mn = w[0], mx = w[0];
        for (int i = 1; i < NEDGE; i++) { mn = fminf(mn, w[i]); mx = fmaxf(mx, w[i]); }
        wmin_s = mn; wmax_s = mx;
    }
    __syncthreads();

    float inv_range = 1.0f / (wmax_s - wmin_s);
    if (tid < NEDGE) w[tid] = (wv - wmin_s) * inv_range;
    __syncthreads();

    if (tid < NBOX) {
        float s = 1.0f;
        for (int rr = 0; rr < tid; rr++) s += w[edge_index(rr, tid)];
        dinv[tid] = 1.0f / sqrtf(s);
    }
    __syncthreads();

    ushort* A = adjbf + (size_t)b * 1024;
    for (int idx = tid; idx < 1024; idx += 192) {
        int r = idx & 31, cc = idx >> 5;
        float v = 0.0f;
        if (r < NBOX && cc < NBOX) {
            if (r == cc) v = dinv[r] * dinv[r];
            else if (r < cc) v = w[edge_index(r, cc)] * dinv[r] * dinv[cc];
        }
        A[idx] = f2bf(v);
    }
}

// ---------------------------------------------------------------------------
// K2: transpose + cvt weights: dst[n*K+k] = bf16(src[k*N+n])
// ---------------------------------------------------------------------------
__global__ void packT_kernel(const float* __restrict__ src, ushort* __restrict__ dst,
                             int K, int N)
{
    int total = K * N;
    for (int idx = blockIdx.x * blockDim.x + threadIdx.x; idx < total;
         idx += gridDim.x * blockDim.x) {
        int n = idx / K, k = idx % K;
        dst[idx] = f2bf(src[(size_t)k * N + n]);
    }
}

// ---------------------------------------------------------------------------
// K2b: streaming feat f32 -> bf16 (removes all cvt VALU from fused staging)
// ---------------------------------------------------------------------------
__global__ __launch_bounds__(256) void cvt_kernel(
    const float* __restrict__ src, ushort* __restrict__ dst, int n8)
{
    for (int i = blockIdx.x * blockDim.x + threadIdx.x; i < n8;
         i += gridDim.x * blockDim.x) {
        float4 a = ((const float4*)src)[2 * i];
        float4 b = ((const float4*)src)[2 * i + 1];
        ushort u[8];
        u[0] = f2bf(a.x); u[1] = f2bf(a.y); u[2] = f2bf(a.z); u[3] = f2bf(a.w);
        u[4] = f2bf(b.x); u[5] = f2bf(b.y); u[6] = f2bf(b.z); u[7] = f2bf(b.w);
        *(int4*)(dst + (size_t)i * 8) = *(int4*)u;
    }
}

// ---------------------------------------------------------------------------
// K3: fused per-1-batch pipeline, 24 KB LDS -> 6 blocks/CU (24 waves).
// ---------------------------------------------------------------------------
__global__ __launch_bounds__(256, 6) void fused_kernel(
    const ushort* __restrict__ Xbf,    // (B,19,512) bf16
    const ushort* __restrict__ adjbf,  // (B,32,32) bf16
    const ushort* __restrict__ W1T,    // (256,512) bf16 [n][k]
    const ushort* __restrict__ W2T,    // (512,256) bf16 [n][k]
    const float*  __restrict__ b1,
    const float*  __restrict__ b2,
    float* __restrict__ out)           // (B,19,512) f32
{
    __shared__ __align__(16) ushort XHs[MP * 256];  // 16384 B (X half / H), swizzled
    __shared__ __align__(16) ushort YsT[64 * 32];   // 4096 B, [ncol][gr], swizzled
    __shared__ __align__(16) ushort AdjS[MP * 64];  // 4096 B, stride 128B, swizzled

    const int tid = threadIdx.x;
    const int lane = tid & 63, wvi = tid >> 6;
    const int b = blockIdx.x;
    const int ncol = wvi * 16 + (lane & 15);
    const int kgrp = lane >> 4;
    const int l15 = lane & 15;

    // stage AdjS: rows = out node cc (0..31), cols = src node r (0..63, 32+ zero)
    {
        int row = tid >> 3, g = tid & 7;
        int4 v = make_int4(0, 0, 0, 0);
        if (g < 4) v = *(const int4*)(adjbf + (size_t)b * 1024 + row * 32 + g * 8);
        int boff = (row * 128 + g * 16) ^ ((row & 7) << 4);
        *(int4*)((char*)AdjS + boff) = v;
    }

    // ================= GEMM1: Y1 = X @ W1 (K=512, two halves) =================
    f32x4 acc1[4][2];
#pragma unroll
    for (int c = 0; c < 4; c++)
#pragma unroll
        for (int m = 0; m < 2; m++) acc1[c][m] = (f32x4){0.f, 0.f, 0.f, 0.f};

    const ushort* xg = Xbf + (size_t)b * NBOX * 512;
    for (int kh = 0; kh < 2; kh++) {
        __syncthreads();   // prev-half A reads done (kh=0: trivial)
#pragma unroll
        for (int p = 0; p < 4; p++) {
            int i = tid + p * 256;          // 32 rows x 32 16B-chunks
            int row = i >> 5, g = i & 31;
            int4 v = make_int4(0, 0, 0, 0);
            if (row < NBOX) v = *(const int4*)(xg + (size_t)row * 512 + kh * 256 + g * 8);
            int boff = (row * 512 + g * 16) ^ ((row & 7) << 4);
            *(int4*)((char*)XHs + boff) = v;
        }
        __syncthreads();

        const ushort* bpb = W1T + (size_t)ncol * 512 + kh * 256 + kgrp * 8;
#pragma unroll
        for (int ks = 0; ks < 8; ks++) {
            short8v bb[4];
#pragma unroll
            for (int c = 0; c < 4; c++)
                bb[c] = *(const short8v*)(bpb + (size_t)c * 64 * 512 + ks * 32);
            short8v a[2];
#pragma unroll
            for (int m = 0; m < 2; m++) {
                int row = m * 16 + l15;
                int boff = (row * 512 + ks * 64 + kgrp * 16) ^ ((row & 7) << 4);
                a[m] = *(const short8v*)((char*)XHs + boff);
            }
#pragma unroll
            for (int c = 0; c < 4; c++)
#pragma unroll
                for (int m = 0; m < 2; m++)
                    acc1[c][m] = __builtin_amdgcn_mfma_f32_16x16x32_bf16(
                        a[m], bb[c], acc1[c][m], 0, 0, 0);
        }
    }

    // ---- agg1: per 64-col chunk: YsT <- bf16(Y1), aggMFMA, sigmoid -> H ----
#pragma unroll
    for (int c = 0; c < 4; c++) {
        __syncthreads();   // prev chunk YsT reads done (c=0: GEMM1 reads done)
#pragma unroll
        for (int m = 0; m < 2; m++) {
            int gr0 = m * 16 + kgrp * 4;
            ushort4 hq;
            hq.x = f2bf(acc1[c][m][0]); hq.y = f2bf(acc1[c][m][1]);
            hq.z = f2bf(acc1[c][m][2]); hq.w = f2bf(acc1[c][m][3]);
            int boff = (ncol * 64 + gr0 * 2) ^ ((ncol & 3) << 4);
            *(ushort4*)((char*)YsT + boff) = hq;
        }
        __syncthreads();
        short8v yb = *(const short8v*)((char*)YsT +
                     ((ncol * 64 + kgrp * 16) ^ ((ncol & 3) << 4)));
        float bv = b1[c * 64 + ncol];
#pragma unroll
        for (int mt = 0; mt < 2; mt++) {
            int ar = mt * 16 + l15;
            short8v af = *(const short8v*)((char*)AdjS +
                         ((ar * 128 + kgrp * 16) ^ ((ar & 7) << 4)));
            f32x4 o = __builtin_amdgcn_mfma_f32_16x16x32_bf16(
                af, yb, (f32x4){0.f, 0.f, 0.f, 0.f}, 0, 0, 0);
#pragma unroll
            for (int j = 0; j < 4; j++) {
                int grp = mt * 16 + kgrp * 4 + j;
                float s = sigm(o[j] + bv);
                int boff = (grp * 512 + (c * 64 + ncol) * 2) ^ ((grp & 7) << 4);
                *(ushort*)((char*)XHs + boff) = f2bf(s);   // H (aliased on X)
            }
        }
    }
    __syncthreads();   // H fully built

    // ============ GEMM2 + agg2: two halves of 4 chunks (256 cols) ============
#pragma unroll 1
    for (int half = 0; half < 2; half++) {
        f32x4 acc[4][2];
#pragma unroll
        for (int c = 0; c < 4; c++)
#pragma unroll
            for (int m = 0; m < 2; m++) acc[c][m] = (f32x4){0.f, 0.f, 0.f, 0.f};

        const ushort* bpb = W2T + (size_t)(half * 256 + ncol) * 256 + kgrp * 8;
#pragma unroll
        for (int ks = 0; ks < 8; ks++) {
            short8v bb[4];
#pragma unroll
            for (int c = 0; c < 4; c++)
                bb[c] = *(const short8v*)(bpb + (size_t)c * 64 * 256 + ks * 32);
            short8v a[2];
#pragma unroll
            for (int m = 0; m < 2; m++) {
                int row = m * 16 + l15;
                int boff = (row * 512 + ks * 64 + kgrp * 16) ^ ((row & 7) << 4);
                a[m] = *(const short8v*)((char*)XHs + boff);
            }
#pragma unroll
            for (int c = 0; c < 4; c++)
#pragma unroll
                for (int m = 0; m < 2; m++)
                    acc[c][m] = __builtin_amdgcn_mfma_f32_16x16x32_bf16(
                        a[m], bb[c], acc[c][m], 0, 0, 0);
        }

#pragma unroll
        for (int c = 0; c < 4; c++) {
            int cg = half * 4 + c;
            __syncthreads();   // prev chunk's YsT reads done
#pragma unroll
            for (int m = 0; m < 2; m++) {
                int gr0 = m * 16 + kgrp * 4;
                ushort4 hq;
                hq.x = f2bf(acc[c][m][0]); hq.y = f2bf(acc[c][m][1]);
                hq.z = f2bf(acc[c][m][2]); hq.w = f2bf(acc[c][m][3]);
                int boff = (ncol * 64 + gr0 * 2) ^ ((ncol & 3) << 4);
                *(ushort4*)((char*)YsT + boff) = hq;
            }
            __syncthreads();
            short8v yb = *(const short8v*)((char*)YsT +
                         ((ncol * 64 + kgrp * 16) ^ ((ncol & 3) << 4)));
            float bv = b2[cg * 64 + ncol];
#pragma unroll
            for (int mt = 0; mt < 2; mt++) {
                int ar = mt * 16 + l15;
                short8v af = *(const short8v*)((char*)AdjS +
                             ((ar * 128 + kgrp * 16) ^ ((ar & 7) << 4)));
                f32x4 o = __builtin_amdgcn_mfma_f32_16x16x32_bf16(
                    af, yb, (f32x4){0.f, 0.f, 0.f, 0.f}, 0, 0, 0);
#pragma unroll
                for (int j = 0; j < 4; j++) {
                    int grp = mt * 16 + kgrp * 4 + j;
                    if (grp < NBOX) {
                        float s = sigm(o[j] + bv);
                        out[((size_t)b * NBOX + grp) * 512 + cg * 64 + ncol] = s;
                    }
                }
            }
        }
    }
}

extern "C" void kernel_launch(void* const* d_in, const int* in_sizes, int n_in,
                              void* d_out, int out_size, void* d_ws, size_t ws_size,
                              hipStream_t stream) {
    const float* loc  = (const float*)d_in[0];
    const float* feat = (const float*)d_in[1];
    const int*   mask = (const int*)d_in[2];
    const float* past = (const float*)d_in[3];
    const float* W1   = (const float*)d_in[4];
    const float* b1   = (const float*)d_in[5];
    const float* W2   = (const float*)d_in[6];
    const float* b2   = (const float*)d_in[7];

    ushort* adjbf = (ushort*)d_ws;                    // 2048*1024 bf16 = 4 MB
    ushort* W1T   = adjbf + (size_t)BATCH * 1024;     // 256*512 bf16
    ushort* W2T   = W1T + 256 * 512;                  // 512*256 bf16
    ushort* Xbf   = W2T + 512 * 256;                  // 2048*19*512 bf16 = 38 MB

    adjbf_kernel<<<BATCH, 192, 0, stream>>>(loc, mask, past, adjbf);
    packT_kernel<<<512, 256, 0, stream>>>(W1, W1T, 512, 256);
    packT_kernel<<<256, 256, 0, stream>>>(W2, W2T, 256, 512);
    cvt_kernel<<<2048, 256, 0, stream>>>(feat, Xbf, BATCH * NBOX * 512 / 8);

    fused_kernel<<<BATCH, 256, 0, stream>>>(Xbf, adjbf, W1T, W2T, b1, b2,
                                            (float*)d_out);
}

// Round 7
// 110.268 us; speedup vs baseline: 1.8417x; 1.8417x over previous
//
#include <hip/hip_runtime.h>
#include <hip/hip_bf16.h>
#include <math.h>

#define NBOX 19
#define NEDGE 171
#define TT 5
#define BATCH 2048
#define GB 2                  // batches per fused block
#define MR (GB * NBOX)        // 38 real rows per block
#define MP 48                 // padded rows (3 M-tiles of 16)

typedef __attribute__((ext_vector_type(8))) short short8v;
typedef __attribute__((ext_vector_type(4))) float f32x4;

// cheap bf16 convert: round-half-up (2 VALU ops vs ~5 for RNE)
static __device__ __forceinline__ ushort f2bf(float f) {
    unsigned int u = __builtin_bit_cast(unsigned int, f);
    return (ushort)((u + 0x8000u) >> 16);
}

static __device__ __forceinline__ float sigm(float x) {
    return __builtin_amdgcn_rcpf(1.0f + __expf(-x));
}

__device__ __forceinline__ int edge_index(int r, int c) {
    return r * (NBOX - 1) - (r * (r - 1)) / 2 + (c - r - 1);
}

// ---------------------------------------------------------------------------
// K1: per-batch normalized adjacency, bf16, padded to 32x32
// ---------------------------------------------------------------------------
__global__ __launch_bounds__(192) void adjbf_kernel(
    const float* __restrict__ loc,
    const int*   __restrict__ mask,
    const float* __restrict__ past,
    ushort* __restrict__ adjbf)
{
    int b = blockIdx.x;
    int tid = threadIdx.x;
    __shared__ float cx[NBOX], cy[NBOX], x0[NBOX], y0[NBOX], ndx[NBOX], ndy[NBOX];
    __shared__ int   mv[NBOX];
    __shared__ float w[NEDGE];
    __shared__ float dinv[NBOX];
    __shared__ float wmin_s, wmax_s;

    if (tid < NBOX) {
        const float* l = loc + ((size_t)b * NBOX + tid) * 5;
        cx[tid] = 0.5f * (l[1] + l[3]);
        cy[tid] = 0.5f * (l[2] + l[4]);
        const float* p0 = past + (((size_t)b * TT + 0) * NBOX + tid) * 6;
        const float* p4 = past + (((size_t)b * TT + (TT - 1)) * NBOX + tid) * 6;
        float cpx0 = (p0[3] - p0[1]) * 1280.0f, cpy0 = (p0[4] - p0[2]) * 720.0f;
        float cpx4 = (p4[3] - p4[1]) * 1280.0f, cpy4 = (p4[4] - p4[2]) * 720.0f;
        float dx = cpx4 - cpx0, dy = cpy4 - cpy0;
        float len = sqrtf(dx * dx + dy * dy);
        if (len == 0.0f) len = 1.0f;
        ndx[tid] = dx / len;
        ndy[tid] = dy / len;
        x0[tid] = cpx0;
        y0[tid] = cpy0;
        mv[tid] = mask[(size_t)b * NBOX + tid];
    }
    __syncthreads();

    float wv = 0.0f;
    if (tid < NEDGE) {
        int rem = tid, rr = 0;
        while (rem >= NBOX - 1 - rr) { rem -= NBOX - 1 - rr; rr++; }
        int r = rr, c = rr + 1 + rem;
        float ddx = cx[r] - cx[c], ddy = cy[r] - cy[c];
        float d = ddx * ddx + ddy * ddy;
        float ax = x0[r] + ndx[r] - x0[c] - ndx[c];
        float ay = y0[r] + ndy[r] - y0[c] - ndy[c];
        float d1 = sqrtf(ax * ax + ay * ay);
        float bx = x0[r] - x0[c], by = y0[r] - y0[c];
        float d2 = sqrtf(bx * bx + by * by);
        float md = d1 - d2;
        wv = expf(-(0.7f * d + 0.3f * md));
        if (!(mv[r] && mv[c])) wv = 0.0f;
        w[tid] = wv;
    }
    __syncthreads();

    if (tid == 0) {
        float mn = w[0], mx = w[0];
        for (int i = 1; i < NEDGE; i++) { mn = fminf(mn, w[i]); mx = fmaxf(mx, w[i]); }
        wmin_s = mn; wmax_s = mx;
    }
    __syncthreads();

    float inv_range = 1.0f / (wmax_s - wmin_s);
    if (tid < NEDGE) w[tid] = (wv - wmin_s) * inv_range;
    __syncthreads();

    if (tid < NBOX) {
        float s = 1.0f;
        for (int rr = 0; rr < tid; rr++) s += w[edge_index(rr, tid)];
        dinv[tid] = 1.0f / sqrtf(s);
    }
    __syncthreads();

    ushort* A = adjbf + (size_t)b * 1024;
    for (int idx = tid; idx < 1024; idx += 192) {
        int r = idx & 31, cc = idx >> 5;
        float v = 0.0f;
        if (r < NBOX && cc < NBOX) {
            if (r == cc) v = dinv[r] * dinv[r];
            else if (r < cc) v = w[edge_index(r, cc)] * dinv[r] * dinv[cc];
        }
        A[idx] = f2bf(v);
    }
}

// ---------------------------------------------------------------------------
// K2: transpose + cvt weights: dst[n*K+k] = bf16(src[k*N+n])
// ---------------------------------------------------------------------------
__global__ void packT_kernel(const float* __restrict__ src, ushort* __restrict__ dst,
                             int K, int N)
{
    int total = K * N;
    for (int idx = blockIdx.x * blockDim.x + threadIdx.x; idx < total;
         idx += gridDim.x * blockDim.x) {
        int n = idx / K, k = idx % K;
        dst[idx] = f2bf(src[(size_t)k * N + n]);
    }
}

// ---------------------------------------------------------------------------
// K3: fused per-2-batch pipeline, 38.9 KB LDS -> 4 blocks/CU (16 waves).
// Only 5 barriers/block: agg transpose (YsT) is intra-wave (each wave owns
// all 48 rows of its 16 columns) so it needs no __syncthreads at all.
// B operands: 2-deep register ring (covers ~250-cyc L2 latency).
// ---------------------------------------------------------------------------
__global__ __launch_bounds__(256, 4) void fused_kernel(
    const float*  __restrict__ feat,   // (B,19,512) f32
    const ushort* __restrict__ adjbf,  // (B,32,32) bf16
    const ushort* __restrict__ W1T,    // (256,512) bf16 [n][k]
    const ushort* __restrict__ W2T,    // (512,256) bf16 [n][k]
    const float*  __restrict__ b1,
    const float*  __restrict__ b2,
    float* __restrict__ out)           // (B,19,512) f32
{
    __shared__ __align__(16) ushort XHs[MP * 256];   // 24576 B (X half-K / H), swizzled
    __shared__ __align__(16) ushort YsT[64 * 64];    // 8192 B, [ncol][gr], per-wave slices
    __shared__ __align__(16) ushort AdjS[MP * 64];   // 6144 B, block-diag 48x64, swizzled

    const int tid = threadIdx.x;
    const int lane = tid & 63, wvi = tid >> 6;
    const int rowbase = blockIdx.x * MR;
    const int bbase = blockIdx.x * GB;
    const int ncol = wvi * 16 + (lane & 15);
    const int kgrp = lane >> 4;
    const int l15 = lane & 15;

    // zero YsT pad rows (gr >= 38 slots must stay zero)
#pragma unroll
    for (int p = 0; p < 2; p++)
        ((int4*)YsT)[tid + p * 256] = make_int4(0, 0, 0, 0);

    // stage block-diagonal adjacency: AdjS[g*19+cc][g*19+r] = A_g[cc][r]
    for (int i = tid; i < MP * 64; i += 256) {
        int row = i >> 6, col = i & 63;
        ushort v = 0;
        if (row < MR) {
            int g = (row >= NBOX) ? 1 : 0;
            int cc = row - g * NBOX;
            int rc = col - g * NBOX;
            if ((unsigned)rc < (unsigned)NBOX)
                v = adjbf[(size_t)(bbase + g) * 1024 + cc * 32 + rc];
        }
        int boff = (row * 128 + col * 2) ^ ((row & 7) << 4);
        *(ushort*)((char*)AdjS + boff) = v;
    }

    // ================= GEMM1: Y1 = X @ W1 (K=512, two halves) =================
    f32x4 acc1[4][3];
#pragma unroll
    for (int c = 0; c < 4; c++)
#pragma unroll
        for (int m = 0; m < 3; m++) acc1[c][m] = (f32x4){0.f, 0.f, 0.f, 0.f};

    for (int kh = 0; kh < 2; kh++) {
        __syncthreads();   // kh=0: YsT/AdjS init visible; kh=1: prev-half reads done
        const float* fg = feat + (size_t)rowbase * 512 + kh * 256;
#pragma unroll
        for (int p = 0; p < 12; p++) {           // 48 rows x 64 float4-slots
            int i = tid + p * 256;
            int row = i >> 6, q = i & 63;
            ushort4 h;
            if (i < MR * 64) {
                float4 v = *(const float4*)(fg + (size_t)row * 512 + q * 4);
                h.x = f2bf(v.x); h.y = f2bf(v.y); h.z = f2bf(v.z); h.w = f2bf(v.w);
            } else {
                h.x = 0; h.y = 0; h.z = 0; h.w = 0;   // zero-pad rows 38..47
            }
            int boff = (row * 512 + q * 8) ^ ((row & 7) << 4);
            *(ushort4*)((char*)XHs + boff) = h;
        }
        __syncthreads();

        const ushort* bpb = W1T + (size_t)ncol * 512 + kh * 256 + kgrp * 8;
        short8v br[3][4];
#pragma unroll
        for (int c = 0; c < 4; c++)
            br[0][c] = *(const short8v*)(bpb + (size_t)c * 64 * 512);
#pragma unroll
        for (int c = 0; c < 4; c++)
            br[1][c] = *(const short8v*)(bpb + (size_t)c * 64 * 512 + 32);
#pragma unroll
        for (int ks = 0; ks < 8; ks++) {
            if (ks < 6) {
#pragma unroll
                for (int c = 0; c < 4; c++)
                    br[(ks + 2) % 3][c] =
                        *(const short8v*)(bpb + (size_t)c * 64 * 512 + (ks + 2) * 32);
            }
            short8v a[3];
#pragma unroll
            for (int m = 0; m < 3; m++) {
                int row = m * 16 + l15;
                int boff = (row * 512 + ks * 64 + kgrp * 16) ^ ((row & 7) << 4);
                a[m] = *(const short8v*)((char*)XHs + boff);
            }
#pragma unroll
            for (int c = 0; c < 4; c++)
#pragma unroll
                for (int m = 0; m < 3; m++)
                    acc1[c][m] = __builtin_amdgcn_mfma_f32_16x16x32_bf16(
                        a[m], br[ks % 3][c], acc1[c][m], 0, 0, 0);
        }
    }
    __syncthreads();   // all GEMM1 A-reads done; H may overwrite X region

    // ---- agg1 (barrier-free): per chunk: YsT <- bf16(Y1), aggMFMA -> H ----
#pragma unroll
    for (int c = 0; c < 4; c++) {
#pragma unroll
        for (int m = 0; m < 3; m++) {
            int gr0 = m * 16 + kgrp * 4;
            ushort4 hq;
            hq.x = f2bf(acc1[c][m][0]); hq.y = f2bf(acc1[c][m][1]);
            hq.z = f2bf(acc1[c][m][2]); hq.w = f2bf(acc1[c][m][3]);
            int boff = (ncol * 128 + gr0 * 2) ^ ((ncol & 7) << 4);
            *(ushort4*)((char*)YsT + boff) = hq;
        }
        // same-wave LDS dependency only: compiler inserts lgkmcnt wait
        short8v yb[2];
#pragma unroll
        for (int ks = 0; ks < 2; ks++)
            yb[ks] = *(const short8v*)((char*)YsT +
                     ((ncol * 128 + ks * 64 + kgrp * 16) ^ ((ncol & 7) << 4)));
        float bv = b1[c * 64 + ncol];
#pragma unroll
        for (int mt = 0; mt < 3; mt++) {
            f32x4 o = (f32x4){0.f, 0.f, 0.f, 0.f};
#pragma unroll
            for (int ks = 0; ks < 2; ks++) {
                int ar = mt * 16 + l15;
                short8v af = *(const short8v*)((char*)AdjS +
                             ((ar * 128 + ks * 64 + kgrp * 16) ^ ((ar & 7) << 4)));
                o = __builtin_amdgcn_mfma_f32_16x16x32_bf16(af, yb[ks], o, 0, 0, 0);
            }
#pragma unroll
            for (int j = 0; j < 4; j++) {
                int grp = mt * 16 + kgrp * 4 + j;
                float s = sigm(o[j] + bv);
                int boff = (grp * 512 + (c * 64 + ncol) * 2) ^ ((grp & 7) << 4);
                *(ushort*)((char*)XHs + boff) = f2bf(s);   // H (aliased on X)
            }
        }
    }
    __syncthreads();   // H fully built before GEMM2 reads

    // ============ GEMM2 + agg2: two halves of 4 chunks (256 cols) ============
#pragma unroll 1
    for (int half = 0; half < 2; half++) {
        f32x4 acc[4][3];
#pragma unroll
        for (int c = 0; c < 4; c++)
#pragma unroll
            for (int m = 0; m < 3; m++) acc[c][m] = (f32x4){0.f, 0.f, 0.f, 0.f};

        const ushort* bpb = W2T + (size_t)(half * 256 + ncol) * 256 + kgrp * 8;
        short8v br[3][4];
#pragma unroll
        for (int c = 0; c < 4; c++)
            br[0][c] = *(const short8v*)(bpb + (size_t)c * 64 * 256);
#pragma unroll
        for (int c = 0; c < 4; c++)
            br[1][c] = *(const short8v*)(bpb + (size_t)c * 64 * 256 + 32);
#pragma unroll
        for (int ks = 0; ks < 8; ks++) {
            if (ks < 6) {
#pragma unroll
                for (int c = 0; c < 4; c++)
                    br[(ks + 2) % 3][c] =
                        *(const short8v*)(bpb + (size_t)c * 64 * 256 + (ks + 2) * 32);
            }
            short8v a[3];
#pragma unroll
            for (int m = 0; m < 3; m++) {
                int row = m * 16 + l15;
                int boff = (row * 512 + ks * 64 + kgrp * 16) ^ ((row & 7) << 4);
                a[m] = *(const short8v*)((char*)XHs + boff);
            }
#pragma unroll
            for (int c = 0; c < 4; c++)
#pragma unroll
                for (int m = 0; m < 3; m++)
                    acc[c][m] = __builtin_amdgcn_mfma_f32_16x16x32_bf16(
                        a[m], br[ks % 3][c], acc[c][m], 0, 0, 0);
        }

        // agg2 (barrier-free, per-wave YsT), direct scalar out stores
#pragma unroll
        for (int c = 0; c < 4; c++) {
            int cg = half * 4 + c;
#pragma unroll
            for (int m = 0; m < 3; m++) {
                int gr0 = m * 16 + kgrp * 4;
                ushort4 hq;
                hq.x = f2bf(acc[c][m][0]); hq.y = f2bf(acc[c][m][1]);
                hq.z = f2bf(acc[c][m][2]); hq.w = f2bf(acc[c][m][3]);
                int boff = (ncol * 128 + gr0 * 2) ^ ((ncol & 7) << 4);
                *(ushort4*)((char*)YsT + boff) = hq;
            }
            short8v yb[2];
#pragma unroll
            for (int ks = 0; ks < 2; ks++)
                yb[ks] = *(const short8v*)((char*)YsT +
                         ((ncol * 128 + ks * 64 + kgrp * 16) ^ ((ncol & 7) << 4)));
            float bv = b2[cg * 64 + ncol];
#pragma unroll
            for (int mt = 0; mt < 3; mt++) {
                f32x4 o = (f32x4){0.f, 0.f, 0.f, 0.f};
#pragma unroll
                for (int ks = 0; ks < 2; ks++) {
                    int ar = mt * 16 + l15;
                    short8v af = *(const short8v*)((char*)AdjS +
                                 ((ar * 128 + ks * 64 + kgrp * 16) ^ ((ar & 7) << 4)));
                    o = __builtin_amdgcn_mfma_f32_16x16x32_bf16(af, yb[ks], o, 0, 0, 0);
                }
#pragma unroll
                for (int j = 0; j < 4; j++) {
                    int grp = mt * 16 + kgrp * 4 + j;
                    if (grp < MR) {
                        float s = sigm(o[j] + bv);
                        out[(size_t)(rowbase + grp) * 512 + cg * 64 + ncol] = s;
                    }
                }
            }
        }
    }
}

extern "C" void kernel_launch(void* const* d_in, const int* in_sizes, int n_in,
                              void* d_out, int out_size, void* d_ws, size_t ws_size,
                              hipStream_t stream) {
    const float* loc  = (const float*)d_in[0];
    const float* feat = (const float*)d_in[1];
    const int*   mask = (const int*)d_in[2];
    const float* past = (const float*)d_in[3];
    const float* W1   = (const float*)d_in[4];
    const float* b1   = (const float*)d_in[5];
    const float* W2   = (const float*)d_in[6];
    const float* b2   = (const float*)d_in[7];

    ushort* adjbf = (ushort*)d_ws;                    // 2048*1024 bf16 = 4 MB
    ushort* W1T   = adjbf + (size_t)BATCH * 1024;     // 256*512 bf16
    ushort* W2T   = W1T + 256 * 512;                  // 512*256 bf16

    adjbf_kernel<<<BATCH, 192, 0, stream>>>(loc, mask, past, adjbf);
    packT_kernel<<<512, 256, 0, stream>>>(W1, W1T, 512, 256);
    packT_kernel<<<256, 256, 0, stream>>>(W2, W2T, 256, 512);

    fused_kernel<<<BATCH / GB, 256, 0, stream>>>(feat, adjbf, W1T, W2T, b1, b2,
                                                 (float*)d_out);
}